// Round 5
// baseline (543.965 us; speedup 1.0000x reference)
//
#include <hip/hip_runtime.h>

#define N_ITEMS 200000
#define EPSV2 1e-16f   // eps on SQUARED norm product: max(sqrt(x),1e-8)=sqrt(max(x,1e-16))
#define INV_TEMP 10.0f
#define NSLOT 16       // loss accumulator slots to spread atomic contention

// Stable softplus, matches jax.nn.softplus = logaddexp(x, 0)
__device__ __forceinline__ float softplus_f(float x) {
    return fmaxf(x, 0.0f) + log1pf(expf(-fabsf(x)));
}

__device__ __forceinline__ float dot8(const float4& a0, const float4& a1,
                                      const float4& b0, const float4& b1) {
    return a0.x * b0.x + a0.y * b0.y + a0.z * b0.z + a0.w * b0.w +
           a1.x * b1.x + a1.y * b1.y + a1.z * b1.z + a1.w * b1.w;
}

__device__ __forceinline__ float4 avg4(const float4& a, const float4& b) {
    return make_float4(0.5f * (a.x + b.x), 0.5f * (a.y + b.y),
                       0.5f * (a.z + b.z), 0.5f * (a.w + b.w));
}

__global__ void mvr_init_ws(float* ws) {
    if (threadIdx.x < NSLOT * 4) ws[threadIdx.x] = 0.0f;
}

// R5: the experiment R2 should have been — flat launch at the PROVEN-safe
// concurrency, with clean stores. 5-round evidence table:
//   looped 27-38% occ: compulsory 512 MB, 2.2 TB/s, 227-245 us (latency-bound)
//   flat+NT (256,6) 54%: INPUT arrays still compulsory 400 MB (locality OK!)
//                        — the +100/+201 MB junk was all NT sub-line RMW
//   flat (256,8) 85%:    gather re-fetch +297 MB -> locality cliff is
//                        between 54% and 85% occupancy
// So: flat, one item-batch per wave, __launch_bounds__(256,6) (R1 measured
// VGPR=40, occ 54%), regular stores. R1 delivered 2.9 TB/s while hauling
// 60% junk traffic; with compulsory-only 512 MB that rate gives ~150-175 us.
// R4 lesson folded in: don't fight the scheduler for MLP; get latency
// hiding from TLP at the highest locality-safe occupancy.
__global__ __launch_bounds__(256, 6) void mvr_main(
    const float* __restrict__ g1, const float* __restrict__ g2,
    const float* __restrict__ s1, const float* __restrict__ s2,
    const float* __restrict__ att_w,
    const int* __restrict__ neg_g, const int* __restrict__ neg_s,
    const int* __restrict__ neg_c,
    float* __restrict__ out, float* __restrict__ loss_acc)
{
    const int tid = threadIdx.x;
    const int lane = tid & 63;
    const int g = lane >> 4;        // item group within wave (0..3)
    const int l = lane & 15;        // lane within group
    const int waveId = (blockIdx.x << 2) + (tid >> 6);
    const int item = (waveId << 2) + g;          // always < N_ITEMS

    // Index loads first: start the idx -> gather chain immediately.
    const int jg = neg_g[item];
    const int js = neg_s[item];
    const int jc = neg_c[item];

    const size_t rb = (size_t)item * 32;   // row in float4 units (128 floats)

    const float4* G1p = (const float4*)g1;
    const float4* G2p = (const float4*)g2;
    const float4* S1p = (const float4*)s1;
    const float4* S2p = (const float4*)s2;
    float4* Op = (float4*)out;

    float4 G1a = G1p[rb + l], G1b = G1p[rb + 16 + l];
    float4 G2a = G2p[rb + l], G2b = G2p[rb + 16 + l];
    float4 S1a = S1p[rb + l], S1b = S1p[rb + 16 + l];
    float4 S2a = S2p[rb + l], S2b = S2p[rb + 16 + l];

    const size_t rg = (size_t)jg * 32, rs = (size_t)js * 32, rc = (size_t)jc * 32;
    float4 Gna = G2p[rg + l], Gnb = G2p[rg + 16 + l];
    float4 Sna = S2p[rs + l], Snb = S2p[rs + 16 + l];
    float4 C1a = S1p[rc + l], C1b = S1p[rc + 16 + l];
    float4 C2a = S2p[rc + l], C2b = S2p[rc + 16 + l];

    // att_w: 256 floats = 64 float4. ga-half: float4 idx l, 16+l; sa-half: 32+l, 48+l.
    const float4* W = (const float4*)att_w;
    const float4 wa0 = W[l], wa1 = W[16 + l];
    const float4 wb0 = W[32 + l], wb1 = W[48 + l];

    float4 GAa = avg4(G1a, G2a), GAb = avg4(G1b, G2b);
    float4 SAa = avg4(S1a, S2a), SAb = avg4(S1b, S2b);
    float4 CNa = avg4(C1a, C2a), CNb = avg4(C1b, C2b);

    float v[16];
    v[0]  = dot8(G1a, G1b, G2a, G2b);   // g1.g2
    v[1]  = dot8(G1a, G1b, G1a, G1b);   // |g1|^2
    v[2]  = dot8(G2a, G2b, G2a, G2b);   // |g2|^2
    v[3]  = dot8(G1a, G1b, Gna, Gnb);   // g1.g2[neg]
    v[4]  = dot8(Gna, Gnb, Gna, Gnb);   // |g2[neg]|^2
    v[5]  = dot8(S1a, S1b, S2a, S2b);
    v[6]  = dot8(S1a, S1b, S1a, S1b);
    v[7]  = dot8(S2a, S2b, S2a, S2b);
    v[8]  = dot8(S1a, S1b, Sna, Snb);
    v[9]  = dot8(Sna, Snb, Sna, Snb);
    v[10] = dot8(GAa, GAb, SAa, SAb);   // ga.sa
    v[11] = dot8(GAa, GAb, GAa, GAb);   // |ga|^2
    v[12] = dot8(SAa, SAb, SAa, SAb);   // |sa|^2
    v[13] = dot8(GAa, GAb, CNa, CNb);   // ga.sa[neg]
    v[14] = dot8(CNa, CNb, CNa, CNb);   // |sa[neg]|^2
    v[15] = dot8(GAa, GAb, wa0, wa1) + dot8(SAa, SAb, wb0, wb1); // att dot

    // Butterfly over the 16 lanes of the group; every lane gets the sums.
    #pragma unroll
    for (int off = 8; off > 0; off >>= 1) {
        #pragma unroll
        for (int k = 0; k < 16; k++)
            v[k] += __shfl_xor(v[k], off, 64);
    }

    // cos = num * rsqrt(max(n1sq*n2sq, 1e-16)): same clamp semantics as
    // num / max(sqrt(n1sq*n2sq), 1e-8), no serial sqrt+div chains.
    const float cgp = v[0] * rsqrtf(fmaxf(v[1] * v[2], EPSV2));
    const float cgn = v[3] * rsqrtf(fmaxf(v[1] * v[4], EPSV2));
    float accG = softplus_f((cgn - cgp) * INV_TEMP);

    const float csp = v[5] * rsqrtf(fmaxf(v[6] * v[7], EPSV2));
    const float csn = v[8] * rsqrtf(fmaxf(v[6] * v[9], EPSV2));
    float accS = softplus_f((csn - csp) * INV_TEMP);

    const float ccp = v[10] * rsqrtf(fmaxf(v[11] * v[12], EPSV2));
    const float ccn = v[13] * rsqrtf(fmaxf(v[11] * v[14], EPSV2));
    float accC = softplus_f((ccn - ccp) * INV_TEMP);

    const float alpha = 1.0f / (1.0f + expf(-v[15]));
    float4 o0, o1;
    o0.x = SAa.x + alpha * (GAa.x - SAa.x);
    o0.y = SAa.y + alpha * (GAa.y - SAa.y);
    o0.z = SAa.z + alpha * (GAa.z - SAa.z);
    o0.w = SAa.w + alpha * (GAa.w - SAa.w);
    o1.x = SAb.x + alpha * (GAb.x - SAb.x);
    o1.y = SAb.y + alpha * (GAb.y - SAb.y);
    o1.z = SAb.z + alpha * (GAb.z - SAb.z);
    o1.w = SAb.w + alpha * (GAb.w - SAb.w);
    Op[rb + l] = o0;
    Op[rb + 16 + l] = o1;

    // All 16 lanes of a group hold identical acc values → summing across
    // groups (xor 16, 32) gives each lane the exact sum of the 4 group values.
    accG += __shfl_xor(accG, 16, 64); accG += __shfl_xor(accG, 32, 64);
    accS += __shfl_xor(accS, 16, 64); accS += __shfl_xor(accS, 32, 64);
    accC += __shfl_xor(accC, 16, 64); accC += __shfl_xor(accC, 32, 64);

    __shared__ float sh[4][3];
    const int wave = tid >> 6;
    if (lane == 0) {
        sh[wave][0] = accG;
        sh[wave][1] = accS;
        sh[wave][2] = accC;
    }
    __syncthreads();
    if (tid == 0) {
        float a = 0.0f, b = 0.0f, c = 0.0f;
        #pragma unroll
        for (int w = 0; w < 4; w++) {
            a += sh[w][0]; b += sh[w][1]; c += sh[w][2];
        }
        // 12500 blocks -> spread atomics over NSLOT slots (4-float stride)
        const int slot = (blockIdx.x & (NSLOT - 1)) * 4;
        atomicAdd(&loss_acc[slot + 0], a);
        atomicAdd(&loss_acc[slot + 1], b);
        atomicAdd(&loss_acc[slot + 2], c);
    }
}

__global__ void mvr_finalize(const float* __restrict__ loss_acc,
                             float* __restrict__ out_scalar) {
    if (threadIdx.x == 0) {
        float t = 0.0f;
        for (int s = 0; s < NSLOT; s++)
            t += loss_acc[s * 4 + 0] + loss_acc[s * 4 + 1] + loss_acc[s * 4 + 2];
        out_scalar[0] = t * (1.0f / (float)N_ITEMS);
    }
}

extern "C" void kernel_launch(void* const* d_in, const int* in_sizes, int n_in,
                              void* d_out, int out_size, void* d_ws, size_t ws_size,
                              hipStream_t stream) {
    const float* g1    = (const float*)d_in[0];
    const float* g2    = (const float*)d_in[1];
    const float* s1    = (const float*)d_in[2];
    const float* s2    = (const float*)d_in[3];
    const float* att_w = (const float*)d_in[4];
    const int*   neg_g = (const int*)d_in[5];
    const int*   neg_s = (const int*)d_in[6];
    const int*   neg_c = (const int*)d_in[7];
    float* out = (float*)d_out;
    float* ws  = (float*)d_ws;   // NSLOT*4 floats: loss partial sums

    mvr_init_ws<<<1, 64, 0, stream>>>(ws);
    // 12500 blocks x 4 waves x 4 items/wave = 200000 items, one pass
    mvr_main<<<12500, 256, 0, stream>>>(g1, g2, s1, s2, att_w,
                                        neg_g, neg_s, neg_c, out, ws);
    mvr_finalize<<<1, 64, 0, stream>>>(ws, out + (size_t)N_ITEMS * 128);
}

// Round 6
// 461.199 us; speedup vs baseline: 1.1795x; 1.1795x over previous
//
#include <hip/hip_runtime.h>

#define N_ITEMS 200000
#define EPSV2 1e-16f   // eps on SQUARED norm product: max(sqrt(x),1e-8)=sqrt(max(x,1e-16))
#define INV_TEMP 10.0f

// Stable softplus, matches jax.nn.softplus = logaddexp(x, 0)
__device__ __forceinline__ float softplus_f(float x) {
    return fmaxf(x, 0.0f) + log1pf(expf(-fabsf(x)));
}

__device__ __forceinline__ float dot8(const float4& a0, const float4& a1,
                                      const float4& b0, const float4& b1) {
    return a0.x * b0.x + a0.y * b0.y + a0.z * b0.z + a0.w * b0.w +
           a1.x * b1.x + a1.y * b1.y + a1.z * b1.z + a1.w * b1.w;
}

__device__ __forceinline__ float4 avg4(const float4& a, const float4& b) {
    return make_float4(0.5f * (a.x + b.x), 0.5f * (a.y + b.y),
                       0.5f * (a.z + b.z), 0.5f * (a.w + b.w));
}

__global__ void mvr_init_ws(float* ws) {
    if (threadIdx.x < 3) ws[threadIdx.x] = 0.0f;
}

// R6. Launch geometry = R0/R3/R4 (3125 blocks x 4 waves, 4 sweeps): the
// proven locality optimum (compulsory 512 MB; every flat variant inflated
// traffic 1.7-2.7x and regressed). Remaining limiter: latency — ~33k
// cycles/wave-iter vs ~800 compute, because the scheduler clusters the 24
// row loads into ~6-8 serialized round trips (VGPR stuck at 64; the
// (256,3) budget alone didn't change scheduling — R4).
// THE change in R6: __builtin_amdgcn_sched_barrier(0) after the full load
// block forces all 27 load results simultaneously live -> RA must assign
// ~96+ VGPRs -> all loads issue back-to-back into one in-flight window.
// Loads ordered seq-first/gathers-last + a second sched_barrier so the
// sequential-only compute (avgs, 10 dots, att dot) overlaps the gather
// round trip (vmcnt(11) wait instead of full drain).
__global__ __launch_bounds__(256, 3) void mvr_main(
    const float* __restrict__ g1, const float* __restrict__ g2,
    const float* __restrict__ s1, const float* __restrict__ s2,
    const float* __restrict__ att_w,
    const int* __restrict__ neg_g, const int* __restrict__ neg_s,
    const int* __restrict__ neg_c,
    float* __restrict__ out, float* __restrict__ loss_acc)
{
    const int tid = threadIdx.x;
    const int lane = tid & 63;
    const int g = lane >> 4;        // item group within wave (0..3)
    const int l = lane & 15;        // lane within group
    const int wavesPerBlock = blockDim.x >> 6;
    const int waveId = blockIdx.x * wavesPerBlock + (tid >> 6);
    const int waveStride = gridDim.x * wavesPerBlock;
    const int stride4 = waveStride * 4;

    // att_w: 256 floats = 64 float4. ga-half: float4 idx l, 16+l; sa-half: 32+l, 48+l.
    const float4* W = (const float4*)att_w;
    const float4 wa0 = W[l], wa1 = W[16 + l];
    const float4 wb0 = W[32 + l], wb1 = W[48 + l];

    const float4* G1p = (const float4*)g1;
    const float4* G2p = (const float4*)g2;
    const float4* S1p = (const float4*)s1;
    const float4* S2p = (const float4*)s2;
    float4* Op = (float4*)out;

    float accG = 0.0f, accS = 0.0f, accC = 0.0f;

    // Prologue: pre-load the first iteration's neg indices.
    int jg, js, jc;
    {
        const int item0 = waveId * 4 + g;
        jg = neg_g[item0];
        js = neg_s[item0];
        jc = neg_c[item0];
    }

    for (int base = waveId * 4; base < N_ITEMS; base += stride4) {
        const int item = base + g;
        const size_t rb = (size_t)item * 32;   // row in float4 units
        const size_t rg = (size_t)jg * 32, rs = (size_t)js * 32, rc = (size_t)jc * 32;

        // ---- LOAD BLOCK: sequential rows first (fast), gathers last ----
        float4 G1a = G1p[rb + l], G1b = G1p[rb + 16 + l];
        float4 G2a = G2p[rb + l], G2b = G2p[rb + 16 + l];
        float4 S1a = S1p[rb + l], S1b = S1p[rb + 16 + l];
        float4 S2a = S2p[rb + l], S2b = S2p[rb + 16 + l];

        float4 Gna = G2p[rg + l], Gnb = G2p[rg + 16 + l];
        float4 Sna = S2p[rs + l], Snb = S2p[rs + 16 + l];
        float4 C1a = S1p[rc + l], C1b = S1p[rc + 16 + l];
        float4 C2a = S2p[rc + l], C2b = S2p[rc + 16 + l];

        // Next iteration's neg indices (independent, full iteration of slack).
        {
            const int nbase = base + stride4;
            const int nitem = (nbase < N_ITEMS) ? (nbase + g) : item;
            jg = neg_g[nitem];
            js = neg_s[nitem];
            jc = neg_c[nitem];
        }

        // Fence: nothing crosses. All 27 load dests are live here -> RA must
        // keep them in distinct VGPRs -> all loads in flight simultaneously.
        __builtin_amdgcn_sched_barrier(0);

        // ---- sequential-only compute (overlaps the gather round trip) ----
        float4 GAa = avg4(G1a, G2a), GAb = avg4(G1b, G2b);
        float4 SAa = avg4(S1a, S2a), SAb = avg4(S1b, S2b);

        float v[16];
        v[0]  = dot8(G1a, G1b, G2a, G2b);   // g1.g2
        v[1]  = dot8(G1a, G1b, G1a, G1b);   // |g1|^2
        v[2]  = dot8(G2a, G2b, G2a, G2b);   // |g2|^2
        v[5]  = dot8(S1a, S1b, S2a, S2b);
        v[6]  = dot8(S1a, S1b, S1a, S1b);
        v[7]  = dot8(S2a, S2b, S2a, S2b);
        v[10] = dot8(GAa, GAb, SAa, SAb);   // ga.sa
        v[11] = dot8(GAa, GAb, GAa, GAb);   // |ga|^2
        v[12] = dot8(SAa, SAb, SAa, SAb);   // |sa|^2
        v[15] = dot8(GAa, GAb, wa0, wa1) + dot8(SAa, SAb, wb0, wb1); // att dot

        // Fence: keep gather-consumers below, so the seq compute above runs
        // under a partial vmcnt wait while gathers are still outstanding.
        __builtin_amdgcn_sched_barrier(0);

        // ---- gather-dependent compute ----
        float4 CNa = avg4(C1a, C2a), CNb = avg4(C1b, C2b);
        v[3]  = dot8(G1a, G1b, Gna, Gnb);   // g1.g2[neg]
        v[4]  = dot8(Gna, Gnb, Gna, Gnb);   // |g2[neg]|^2
        v[8]  = dot8(S1a, S1b, Sna, Snb);
        v[9]  = dot8(Sna, Snb, Sna, Snb);
        v[13] = dot8(GAa, GAb, CNa, CNb);   // ga.sa[neg]
        v[14] = dot8(CNa, CNb, CNa, CNb);   // |sa[neg]|^2

        // Butterfly over the 16 lanes of the group; every lane gets the sums.
        #pragma unroll
        for (int off = 8; off > 0; off >>= 1) {
            #pragma unroll
            for (int k = 0; k < 16; k++)
                v[k] += __shfl_xor(v[k], off, 64);
        }

        // cos = num * rsqrt(max(n1sq*n2sq, 1e-16)): same clamp semantics as
        // num / max(sqrt(n1sq*n2sq), 1e-8).
        const float cgp = v[0] * rsqrtf(fmaxf(v[1] * v[2], EPSV2));
        const float cgn = v[3] * rsqrtf(fmaxf(v[1] * v[4], EPSV2));
        accG += softplus_f((cgn - cgp) * INV_TEMP);

        const float csp = v[5] * rsqrtf(fmaxf(v[6] * v[7], EPSV2));
        const float csn = v[8] * rsqrtf(fmaxf(v[6] * v[9], EPSV2));
        accS += softplus_f((csn - csp) * INV_TEMP);

        const float ccp = v[10] * rsqrtf(fmaxf(v[11] * v[12], EPSV2));
        const float ccn = v[13] * rsqrtf(fmaxf(v[11] * v[14], EPSV2));
        accC += softplus_f((ccn - ccp) * INV_TEMP);

        const float alpha = 1.0f / (1.0f + expf(-v[15]));
        float4 o0, o1;
        o0.x = SAa.x + alpha * (GAa.x - SAa.x);
        o0.y = SAa.y + alpha * (GAa.y - SAa.y);
        o0.z = SAa.z + alpha * (GAa.z - SAa.z);
        o0.w = SAa.w + alpha * (GAa.w - SAa.w);
        o1.x = SAb.x + alpha * (GAb.x - SAb.x);
        o1.y = SAb.y + alpha * (GAb.y - SAb.y);
        o1.z = SAb.z + alpha * (GAb.z - SAb.z);
        o1.w = SAb.w + alpha * (GAb.w - SAb.w);
        Op[rb + l] = o0;
        Op[rb + 16 + l] = o1;
    }

    // All 16 lanes of a group hold identical acc values → summing across
    // groups (xor 16, 32) gives each lane the exact sum of the 4 group values.
    accG += __shfl_xor(accG, 16, 64); accG += __shfl_xor(accG, 32, 64);
    accS += __shfl_xor(accS, 16, 64); accS += __shfl_xor(accS, 32, 64);
    accC += __shfl_xor(accC, 16, 64); accC += __shfl_xor(accC, 32, 64);

    __shared__ float sh[4][3];
    const int wave = tid >> 6;
    if (lane == 0) {
        sh[wave][0] = accG;
        sh[wave][1] = accS;
        sh[wave][2] = accC;
    }
    __syncthreads();
    if (tid == 0) {
        float a = 0.0f, b = 0.0f, c = 0.0f;
        #pragma unroll
        for (int w = 0; w < 4; w++) {
            a += sh[w][0]; b += sh[w][1]; c += sh[w][2];
        }
        atomicAdd(&loss_acc[0], a);
        atomicAdd(&loss_acc[1], b);
        atomicAdd(&loss_acc[2], c);
    }
}

__global__ void mvr_finalize(const float* __restrict__ loss_acc,
                             float* __restrict__ out_scalar) {
    if (threadIdx.x == 0) {
        out_scalar[0] = (loss_acc[0] + loss_acc[1] + loss_acc[2]) * (1.0f / (float)N_ITEMS);
    }
}

extern "C" void kernel_launch(void* const* d_in, const int* in_sizes, int n_in,
                              void* d_out, int out_size, void* d_ws, size_t ws_size,
                              hipStream_t stream) {
    const float* g1    = (const float*)d_in[0];
    const float* g2    = (const float*)d_in[1];
    const float* s1    = (const float*)d_in[2];
    const float* s2    = (const float*)d_in[3];
    const float* att_w = (const float*)d_in[4];
    const int*   neg_g = (const int*)d_in[5];
    const int*   neg_s = (const int*)d_in[6];
    const int*   neg_c = (const int*)d_in[7];
    float* out = (float*)d_out;
    float* ws  = (float*)d_ws;   // 3 floats: loss partial sums

    mvr_init_ws<<<1, 64, 0, stream>>>(ws);
    // 3125 blocks × 4 waves × 4 items/wave = 50000 items/sweep → exactly 4 sweeps
    mvr_main<<<3125, 256, 0, stream>>>(g1, g2, s1, s2, att_w,
                                       neg_g, neg_s, neg_c, out, ws);
    mvr_finalize<<<1, 64, 0, stream>>>(ws, out + (size_t)N_ITEMS * 128);
}